// Round 10
// baseline (123.459 us; speedup 1.0000x reference)
//
#include <hip/hip_runtime.h>
#include <hip/hip_bf16.h>

// B=64, T=128, D=512. gates = x @ w_ih^T per t; f-gate unused (c0=0).
// K1: per-(t, 64-col) block, 4 waves, reg-staged w (global->VGPR->cvt->LDS).
//     Substage order cg-outer/kh-inner: ss = cg*6 + kh*3 + g, so each w row's
//     two 1KB halves are fetched ~3 substages apart (DRAM page-warm), and
//     accumulators live only per-cg (acc[3] = 12 VGPR; h stored per cg).
//     x frags reloaded from L2 per (cg,kh) - 8 LOADX, cvt hidden under DMA.
//     One barrier per substage; depth-2 rs prefetch; bf16x3 MFMA.
// K2: in-place softmax(20*h).

#define B_ 64
#define T_ 128
#define D_ 512

typedef float f32x4_t __attribute__((ext_vector_type(4)));
typedef __bf16 bf16x8_t __attribute__((ext_vector_type(8)));
typedef unsigned short u16x8_t __attribute__((ext_vector_type(8)));
typedef unsigned short u16x4_t __attribute__((ext_vector_type(4)));

#define SWZ(r) ((unsigned)(((r) & 7) << 4))

// Round-to-nearest split: f = hi + lo + O(2^-18 |f|).
__device__ __forceinline__ void cvt8(float4 a, float4 b, u16x8_t& hi, u16x8_t& lo) {
  float f[8] = {a.x, a.y, a.z, a.w, b.x, b.y, b.z, b.w};
#pragma unroll
  for (int j = 0; j < 8; ++j) {
    __bf16 h = (__bf16)f[j];
    hi[j] = __builtin_bit_cast(unsigned short, h);
    float r = f[j] - (float)h;
    lo[j] = __builtin_bit_cast(unsigned short, (__bf16)r);
  }
}

__device__ __forceinline__ void cvt4(float4 v, u16x4_t& hi, u16x4_t& lo) {
  float f[4] = {v.x, v.y, v.z, v.w};
#pragma unroll
  for (int j = 0; j < 4; ++j) {
    __bf16 h = (__bf16)f[j];
    hi[j] = __builtin_bit_cast(unsigned short, h);
    float r = f[j] - (float)h;
    lo[j] = __builtin_bit_cast(unsigned short, (__bf16)r);
  }
}

__device__ __forceinline__ f32x4_t mfma16(u16x8_t a, u16x8_t b, f32x4_t c) {
  return __builtin_amdgcn_mfma_f32_16x16x32_bf16(
      __builtin_bit_cast(bf16x8_t, a), __builtin_bit_cast(bf16x8_t, b), c, 0, 0, 0);
}

__device__ __forceinline__ float sigmoid_f(float v) { return 1.0f / (1.0f + __expf(-v)); }
__device__ __forceinline__ float tanh_f(float v) { return 1.0f - 2.0f / (__expf(2.0f * v) + 1.0f); }

// Grid 1024 = 128 t x 8 d-tiles. Wave wv stages rows wv*4..+4, computes b-rows wv*16..+16.
__global__ __launch_bounds__(256, 2) void lstm_gates_kernel(
    const float* __restrict__ x, const float* __restrict__ w, float* __restrict__ out) {
  __shared__ char lds[2][16384];  // 16 rows x 1024B (256 hi-bf16 + 256 lo-bf16)
  const int lane = threadIdx.x & 63;
  const int wv = threadIdx.x >> 6;
  const int bid = blockIdx.x;
  // XCD swizzle: 8 d-tiles of one t share an XCD -> x[t] L2-resident.
  const int work = (bid & 7) * 128 + (bid >> 3);
  const int t = work >> 3;
  const int d0 = (work & 7) << 6;

  const int c = lane & 15;   // frag row/col index
  const int kg = lane >> 4;  // k-subgroup 0..3

  // LDS row layout (1024B): [st 0..7][hi 64B | lo 64B], linear byte =
  // st*128 + part*64 + kgx*16 + e*2, physically XOR'd by SWZ(row).
  const int kl = lane * 4;  // float index within 256-float K-half
  const unsigned wst = (unsigned)(((kl >> 5) & 7) * 128);
  const unsigned wlow = (unsigned)((((kl >> 3) & 3) * 16) + ((kl & 4) << 1));
  unsigned wa_hi[4], wa_lo[4];
#pragma unroll
  for (int i = 0; i < 4; ++i) {
    const int rl = wv * 4 + i;
    wa_hi[i] = (unsigned)(rl * 1024) + wst + (wlow ^ SWZ(rl));
    wa_lo[i] = (unsigned)(rl * 1024) + wst + ((wlow + 64) ^ SWZ(rl));
  }
  // Read side: col c, k-step st, group kg.
  const unsigned q_hi = ((unsigned)(kg * 16)) ^ SWZ(c);
  const unsigned q_lo = ((unsigned)(kg * 16 + 64)) ^ SWZ(c);
  const unsigned rbase = (unsigned)(c * 1024);

  const int grow[3] = {0, 1024, 1536};  // gate row bases i, g(2D), o(3D); f skipped
  const char* wt = (const char*)w + ((size_t)t << 22) + (size_t)d0 * 2048;

  f32x4_t acc[3];  // per-cg gates i,g,o (static indices only)
#pragma unroll
  for (int g = 0; g < 3; ++g) acc[g] = (f32x4_t){0.f, 0.f, 0.f, 0.f};

  u16x8_t xh[8], xl[8];
  float4 rs0[4], rs1[4];

  // x frags for K-half KH: b-row wv*16+c, k = KH*256 + st*32 + kg*8 + j.
#define LOADX(KH)                                                                         \
  do {                                                                                    \
    const float* xr_ = x + (((size_t)(wv * 16 + c) * T_ + t) << 9) + (KH) * 256 + kg * 8; \
    _Pragma("unroll") for (int st_ = 0; st_ < 8; ++st_) {                                 \
      float4 a_ = *(const float4*)(xr_ + st_ * 32);                                       \
      float4 b_ = *(const float4*)(xr_ + st_ * 32 + 4);                                   \
      cvt8(a_, b_, xh[st_], xl[st_]);                                                     \
    }                                                                                     \
  } while (0)

  // substage SS = cg*6 + kh*3 + g: rows grow[g]+cg*16+wv*4..+4, K-half kh.
#define WOFF(SS)                                                                \
  ((size_t)(grow[(SS) % 3] + ((SS) / 6) * 16 + wv * 4) * 2048 +                 \
   (size_t)(((SS) / 3) & 1) * 1024)

#define ISSUE(SS, RS)                                                           \
  do {                                                                          \
    const char* gb_ = wt + WOFF(SS) + lane * 16;                                \
    _Pragma("unroll") for (int i_ = 0; i_ < 4; ++i_)                            \
        RS[i_] = *(const float4*)(gb_ + (size_t)i_ * 2048);                     \
  } while (0)

#define WRITE(SS, RS)                                                           \
  do {                                                                          \
    char* lb_ = &lds[(SS) & 1][0];                                              \
    _Pragma("unroll") for (int i_ = 0; i_ < 4; ++i_) {                          \
      u16x4_t h_, l_;                                                           \
      cvt4(RS[i_], h_, l_);                                                     \
      *(u16x4_t*)(lb_ + wa_hi[i_]) = h_;                                        \
      *(u16x4_t*)(lb_ + wa_lo[i_]) = l_;                                        \
    }                                                                           \
  } while (0)

#define BARRIER asm volatile("s_waitcnt lgkmcnt(0)\n\ts_barrier" ::: "memory")

#define COMPUTE(SS)                                                             \
  do {                                                                          \
    const char* lb_ = &lds[(SS) & 1][0];                                        \
    _Pragma("unroll") for (int st_ = 0; st_ < 8; ++st_) {                       \
      u16x8_t wh_ = *(const u16x8_t*)(lb_ + rbase + st_ * 128 + q_hi);          \
      u16x8_t wl_ = *(const u16x8_t*)(lb_ + rbase + st_ * 128 + q_lo);          \
      acc[(SS) % 3] = mfma16(xh[st_], wh_, acc[(SS) % 3]);                      \
      acc[(SS) % 3] = mfma16(xh[st_], wl_, acc[(SS) % 3]);                      \
      acc[(SS) % 3] = mfma16(xl[st_], wh_, acc[(SS) % 3]);                      \
    }                                                                           \
  } while (0)

#define STEP(SS, RS)                        \
  WRITE(SS, RS);                            \
  if ((SS) + 2 < 24) ISSUE((SS) + 2, RS);   \
  BARRIER;                                  \
  COMPUTE(SS)

  // Per-cg epilogue: LSTM activation, store 16 cols, reset acc.
#define EPILOG(CG)                                                              \
  do {                                                                          \
    _Pragma("unroll") for (int j_ = 0; j_ < 4; ++j_) {                          \
      float iv_ = acc[0][j_], gv_ = acc[1][j_], ov_ = acc[2][j_];               \
      float cc_ = sigmoid_f(iv_) * tanh_f(gv_);                                 \
      float h_ = sigmoid_f(ov_) * tanh_f(cc_);                                  \
      int b_ = wv * 16 + kg * 4 + j_;                                           \
      out[(((size_t)b_ * T_ + t) << 9) + d0 + (CG) * 16 + c] = h_;              \
    }                                                                           \
    _Pragma("unroll") for (int g_ = 0; g_ < 3; ++g_)                            \
        acc[g_] = (f32x4_t){0.f, 0.f, 0.f, 0.f};                                \
  } while (0)

  ISSUE(0, rs0);
  ISSUE(1, rs1);

  LOADX(0); STEP(0, rs0);  STEP(1, rs1);  STEP(2, rs0);
  LOADX(1); STEP(3, rs1);  STEP(4, rs0);  STEP(5, rs1);
  EPILOG(0);
  LOADX(0); STEP(6, rs0);  STEP(7, rs1);  STEP(8, rs0);
  LOADX(1); STEP(9, rs1);  STEP(10, rs0); STEP(11, rs1);
  EPILOG(1);
  LOADX(0); STEP(12, rs0); STEP(13, rs1); STEP(14, rs0);
  LOADX(1); STEP(15, rs1); STEP(16, rs0); STEP(17, rs1);
  EPILOG(2);
  LOADX(0); STEP(18, rs0); STEP(19, rs1); STEP(20, rs0);
  LOADX(1); STEP(21, rs1); STEP(22, rs0); STEP(23, rs1);
  EPILOG(3);

#undef EPILOG
#undef STEP
#undef COMPUTE
#undef WRITE
#undef ISSUE
#undef WOFF
#undef LOADX
}

// One wave per (b,t) row of 512; in-place softmax(20*h).
__global__ __launch_bounds__(256) void softmax_kernel(float* __restrict__ io) {
  const int lane = threadIdx.x & 63;
  const int row = blockIdx.x * 4 + (threadIdx.x >> 6);
  float* p = io + ((size_t)row << 9);
  float4 v0 = *(const float4*)(p + lane * 4);
  float4 v1 = *(const float4*)(p + 256 + lane * 4);
  float l[8] = {20.f * v0.x, 20.f * v0.y, 20.f * v0.z, 20.f * v0.w,
                20.f * v1.x, 20.f * v1.y, 20.f * v1.z, 20.f * v1.w};
  float m = l[0];
#pragma unroll
  for (int j = 1; j < 8; ++j) m = fmaxf(m, l[j]);
#pragma unroll
  for (int o = 32; o > 0; o >>= 1) m = fmaxf(m, __shfl_xor(m, o, 64));
  float e[8], s = 0.f;
#pragma unroll
  for (int j = 0; j < 8; ++j) {
    e[j] = __expf(l[j] - m);
    s += e[j];
  }
#pragma unroll
  for (int o = 32; o > 0; o >>= 1) s += __shfl_xor(s, o, 64);
  float inv = 1.0f / s;
  float4 o0 = {e[0] * inv, e[1] * inv, e[2] * inv, e[3] * inv};
  float4 o1 = {e[4] * inv, e[5] * inv, e[6] * inv, e[7] * inv};
  *(float4*)(p + lane * 4) = o0;
  *(float4*)(p + 256 + lane * 4) = o1;
}

extern "C" void kernel_launch(void* const* d_in, const int* in_sizes, int n_in,
                              void* d_out, int out_size, void* d_ws, size_t ws_size,
                              hipStream_t stream) {
  const float* x = (const float*)d_in[0];
  const float* w = (const float*)d_in[1];
  float* out = (float*)d_out;
  lstm_gates_kernel<<<T_ * 8, 256, 0, stream>>>(x, w, out);
  softmax_kernel<<<(B_ * T_) / 4, 256, 0, stream>>>(out);
}

// Round 11
// 103.669 us; speedup vs baseline: 1.1909x; 1.1909x over previous
//
#include <hip/hip_runtime.h>
#include <hip/hip_bf16.h>

// B=64, T=128, D=512. gates = x @ w_ih^T per t; f-gate unused (c0=0).
// K1: per-(t, 64-col) block, 4 waves, reg-staged w (global->VGPR->cvt->LDS).
//     Substage = (cg, gate) over FULL K: each wave stages its 4 w-rows as
//     full 2KB contiguous reads (8 x dwordx4/lane; 32KB contiguous per block
//     per substage -> max DRAM page sequentiality). 12 substages, LDS dbuf
//     2x32KB, depth-1 single rs set. x frags resident in 128 VGPRs (loaded
//     once). acc[3] per cg, per-cg epilogue. bf16x3 MFMA. One barrier/substage.
// K2: in-place softmax(20*h).

#define B_ 64
#define T_ 128
#define D_ 512

typedef float f32x4_t __attribute__((ext_vector_type(4)));
typedef __bf16 bf16x8_t __attribute__((ext_vector_type(8)));
typedef unsigned short u16x8_t __attribute__((ext_vector_type(8)));
typedef unsigned short u16x4_t __attribute__((ext_vector_type(4)));

#define SWZ(r) ((unsigned)(((r) & 7) << 4))

// Round-to-nearest split: f = hi + lo + O(2^-18 |f|).
__device__ __forceinline__ void cvt8(float4 a, float4 b, u16x8_t& hi, u16x8_t& lo) {
  float f[8] = {a.x, a.y, a.z, a.w, b.x, b.y, b.z, b.w};
#pragma unroll
  for (int j = 0; j < 8; ++j) {
    __bf16 h = (__bf16)f[j];
    hi[j] = __builtin_bit_cast(unsigned short, h);
    float r = f[j] - (float)h;
    lo[j] = __builtin_bit_cast(unsigned short, (__bf16)r);
  }
}

__device__ __forceinline__ void cvt4(float4 v, u16x4_t& hi, u16x4_t& lo) {
  float f[4] = {v.x, v.y, v.z, v.w};
#pragma unroll
  for (int j = 0; j < 4; ++j) {
    __bf16 h = (__bf16)f[j];
    hi[j] = __builtin_bit_cast(unsigned short, h);
    float r = f[j] - (float)h;
    lo[j] = __builtin_bit_cast(unsigned short, (__bf16)r);
  }
}

__device__ __forceinline__ f32x4_t mfma16(u16x8_t a, u16x8_t b, f32x4_t c) {
  return __builtin_amdgcn_mfma_f32_16x16x32_bf16(
      __builtin_bit_cast(bf16x8_t, a), __builtin_bit_cast(bf16x8_t, b), c, 0, 0, 0);
}

__device__ __forceinline__ float sigmoid_f(float v) { return 1.0f / (1.0f + __expf(-v)); }
__device__ __forceinline__ float tanh_f(float v) { return 1.0f - 2.0f / (__expf(2.0f * v) + 1.0f); }

// Grid 1024 = 128 t x 8 d-tiles. Wave wv stages w-rows wv*4..+4, computes b-rows wv*16..+16.
__global__ __launch_bounds__(256, 2) void lstm_gates_kernel(
    const float* __restrict__ x, const float* __restrict__ w, float* __restrict__ out) {
  __shared__ char lds[2][32768];  // 16 rows x 2KB (16 steps x [hi 64B | lo 64B])
  const int lane = threadIdx.x & 63;
  const int wv = threadIdx.x >> 6;
  const int bid = blockIdx.x;
  // XCD swizzle: 8 d-tiles of one t share an XCD -> x[t] L2-resident.
  const int work = (bid & 7) * 128 + (bid >> 3);
  const int t = work >> 3;
  const int d0 = (work & 7) << 6;

  const int c = lane & 15;   // frag row/col index
  const int kg = lane >> 4;  // k-subgroup 0..3

  // ---- x A-frags, full K, resident (128 VGPR). b-row wv*16+c, k = st*32+kg*8+j.
  const float* xrow = x + (((size_t)(wv * 16 + c) * T_ + t) << 9) + kg * 8;
  u16x8_t xh[16], xl[16];
#pragma unroll
  for (int st = 0; st < 16; ++st) {
    float4 a = *(const float4*)(xrow + st * 32);
    float4 b = *(const float4*)(xrow + st * 32 + 4);
    cvt8(a, b, xh[st], xl[st]);
  }

  // ---- LDS write addrs. Load i (i=0..7): row rl = wv*4 + (i>>1), chunk q = i&1,
  // floats f0 = q*256 + lane*4 -> step st_w = q*8 + (lane>>3), elem e0 = (lane&7)*4.
  // Linear low-byte (within 128B step blk) = part*64 + (lane&7)*8, phys ^= SWZ(rl).
  unsigned wa_hi[8];
#pragma unroll
  for (int i = 0; i < 8; ++i) {
    const int rl = wv * 4 + (i >> 1);
    const unsigned stw = (unsigned)((i & 1) * 8 + (lane >> 3));
    wa_hi[i] = (unsigned)(rl * 2048) + stw * 128 +
               (((unsigned)((lane & 7) * 8)) ^ SWZ(rl));
  }
  // Read side: col c, step st, group kg; lo = hi ^ 64 (bit 6 = part).
  const unsigned q_hi = ((unsigned)(kg * 16)) ^ SWZ(c);
  const unsigned rbase = (unsigned)(c * 2048);

  const int grow[3] = {0, 1024, 1536};  // gate row bases i, g(2D), o(3D); f skipped
  const char* wt = (const char*)w + ((size_t)t << 22) + (size_t)d0 * 2048;

  f32x4_t acc[3];
#pragma unroll
  for (int g = 0; g < 3; ++g) acc[g] = (f32x4_t){0.f, 0.f, 0.f, 0.f};

  float4 rs[8];  // single staging set: 4 rows x 2KB (8 x 16B per lane)

  // substage SS = cg*3 + g: rows grow[g] + cg*16 + wv*4 .. +4, full K.
#define WOFF(SS) ((size_t)(grow[(SS) % 3] + ((SS) / 3) * 16 + wv * 4) * 2048)

#define ISSUE(SS)                                                               \
  do {                                                                          \
    const char* gb_ = wt + WOFF(SS) + lane * 16;                                \
    _Pragma("unroll") for (int i_ = 0; i_ < 8; ++i_)                            \
        rs[i_] = *(const float4*)(gb_ + (i_ >> 1) * 2048 + (i_ & 1) * 1024);    \
  } while (0)

#define WRITE(SS)                                                               \
  do {                                                                          \
    char* lb_ = &lds[(SS) & 1][0];                                              \
    _Pragma("unroll") for (int i_ = 0; i_ < 8; ++i_) {                          \
      u16x4_t h_, l_;                                                           \
      cvt4(rs[i_], h_, l_);                                                     \
      *(u16x4_t*)(lb_ + wa_hi[i_]) = h_;                                        \
      *(u16x4_t*)(lb_ + (wa_hi[i_] ^ 64u)) = l_;                                \
    }                                                                           \
  } while (0)

#define BARRIER asm volatile("s_waitcnt lgkmcnt(0)\n\ts_barrier" ::: "memory")

#define COMPUTE(SS)                                                             \
  do {                                                                          \
    const char* lb_ = &lds[(SS) & 1][0];                                        \
    _Pragma("unroll") for (int st_ = 0; st_ < 16; ++st_) {                      \
      u16x8_t wh_ = *(const u16x8_t*)(lb_ + rbase + st_ * 128 + q_hi);          \
      u16x8_t wl_ = *(const u16x8_t*)(lb_ + rbase + st_ * 128 + (q_hi ^ 64u));  \
      acc[(SS) % 3] = mfma16(xh[st_], wh_, acc[(SS) % 3]);                      \
      acc[(SS) % 3] = mfma16(xh[st_], wl_, acc[(SS) % 3]);                      \
      acc[(SS) % 3] = mfma16(xl[st_], wh_, acc[(SS) % 3]);                      \
    }                                                                           \
  } while (0)

  // STEP: write current (data-dep waits its loads), immediately re-issue the
  // next substage into the freed rs set (lands during COMPUTE), one barrier,
  // then VMEM-free compute.
#define STEP(SS)                     \
  WRITE(SS);                         \
  if ((SS) + 1 < 12) ISSUE((SS) + 1); \
  BARRIER;                           \
  COMPUTE(SS)

  // Per-cg epilogue: LSTM activation, store 16 cols, reset acc.
#define EPILOG(CG)                                                              \
  do {                                                                          \
    _Pragma("unroll") for (int j_ = 0; j_ < 4; ++j_) {                          \
      float iv_ = acc[0][j_], gv_ = acc[1][j_], ov_ = acc[2][j_];               \
      float cc_ = sigmoid_f(iv_) * tanh_f(gv_);                                 \
      float h_ = sigmoid_f(ov_) * tanh_f(cc_);                                  \
      int b_ = wv * 16 + kg * 4 + j_;                                           \
      out[(((size_t)b_ * T_ + t) << 9) + d0 + (CG) * 16 + c] = h_;              \
    }                                                                           \
    _Pragma("unroll") for (int g_ = 0; g_ < 3; ++g_)                            \
        acc[g_] = (f32x4_t){0.f, 0.f, 0.f, 0.f};                                \
  } while (0)

  ISSUE(0);
  STEP(0);  STEP(1);  STEP(2);  EPILOG(0);
  STEP(3);  STEP(4);  STEP(5);  EPILOG(1);
  STEP(6);  STEP(7);  STEP(8);  EPILOG(2);
  STEP(9);  STEP(10); STEP(11); EPILOG(3);

#undef EPILOG
#undef STEP
#undef COMPUTE
#undef WRITE
#undef ISSUE
#undef WOFF
}

// One wave per (b,t) row of 512; in-place softmax(20*h).
__global__ __launch_bounds__(256) void softmax_kernel(float* __restrict__ io) {
  const int lane = threadIdx.x & 63;
  const int row = blockIdx.x * 4 + (threadIdx.x >> 6);
  float* p = io + ((size_t)row << 9);
  float4 v0 = *(const float4*)(p + lane * 4);
  float4 v1 = *(const float4*)(p + 256 + lane * 4);
  float l[8] = {20.f * v0.x, 20.f * v0.y, 20.f * v0.z, 20.f * v0.w,
                20.f * v1.x, 20.f * v1.y, 20.f * v1.z, 20.f * v1.w};
  float m = l[0];
#pragma unroll
  for (int j = 1; j < 8; ++j) m = fmaxf(m, l[j]);
#pragma unroll
  for (int o = 32; o > 0; o >>= 1) m = fmaxf(m, __shfl_xor(m, o, 64));
  float e[8], s = 0.f;
#pragma unroll
  for (int j = 0; j < 8; ++j) {
    e[j] = __expf(l[j] - m);
    s += e[j];
  }
#pragma unroll
  for (int o = 32; o > 0; o >>= 1) s += __shfl_xor(s, o, 64);
  float inv = 1.0f / s;
  float4 o0 = {e[0] * inv, e[1] * inv, e[2] * inv, e[3] * inv};
  float4 o1 = {e[4] * inv, e[5] * inv, e[6] * inv, e[7] * inv};
  *(float4*)(p + lane * 4) = o0;
  *(float4*)(p + 256 + lane * 4) = o1;
}

extern "C" void kernel_launch(void* const* d_in, const int* in_sizes, int n_in,
                              void* d_out, int out_size, void* d_ws, size_t ws_size,
                              hipStream_t stream) {
  const float* x = (const float*)d_in[0];
  const float* w = (const float*)d_in[1];
  float* out = (float*)d_out;
  lstm_gates_kernel<<<T_ * 8, 256, 0, stream>>>(x, w, out);
  softmax_kernel<<<(B_ * T_) / 4, 256, 0, stream>>>(out);
}

// Round 12
// 102.164 us; speedup vs baseline: 1.2084x; 1.0147x over previous
//
#include <hip/hip_runtime.h>
#include <hip/hip_bf16.h>

// B=64, T=128, D=512. gates = x @ w_ih^T per t; f-gate unused (c0=0).
// K1: per-(t, 64-col) block, 4 waves, reg-staged w (global->VGPR->cvt->LDS).
//     r9 structure with kh-INNER substage order: ss = cg*6 + g*2 + kh, so the
//     two 1KB halves of each 2KB w-row are issued back-to-back (DRAM page
//     fetched once, fully). Depth-2 rs prefetch, 2x16KB dbuf LDS, one barrier
//     per substage. x frags full-K resident (128 VGPR, loaded once).
//     acc[3] per-cg + per-cg epilogue. bf16x3 MFMA (hi*hi + hi*lo + lo*hi).
// K2: in-place softmax(20*h).

#define B_ 64
#define T_ 128
#define D_ 512

typedef float f32x4_t __attribute__((ext_vector_type(4)));
typedef __bf16 bf16x8_t __attribute__((ext_vector_type(8)));
typedef unsigned short u16x8_t __attribute__((ext_vector_type(8)));
typedef unsigned short u16x4_t __attribute__((ext_vector_type(4)));

#define SWZ(r) ((unsigned)(((r) & 7) << 4))

// Round-to-nearest split: f = hi + lo + O(2^-18 |f|).
__device__ __forceinline__ void cvt8(float4 a, float4 b, u16x8_t& hi, u16x8_t& lo) {
  float f[8] = {a.x, a.y, a.z, a.w, b.x, b.y, b.z, b.w};
#pragma unroll
  for (int j = 0; j < 8; ++j) {
    __bf16 h = (__bf16)f[j];
    hi[j] = __builtin_bit_cast(unsigned short, h);
    float r = f[j] - (float)h;
    lo[j] = __builtin_bit_cast(unsigned short, (__bf16)r);
  }
}

__device__ __forceinline__ void cvt4(float4 v, u16x4_t& hi, u16x4_t& lo) {
  float f[4] = {v.x, v.y, v.z, v.w};
#pragma unroll
  for (int j = 0; j < 4; ++j) {
    __bf16 h = (__bf16)f[j];
    hi[j] = __builtin_bit_cast(unsigned short, h);
    float r = f[j] - (float)h;
    lo[j] = __builtin_bit_cast(unsigned short, (__bf16)r);
  }
}

__device__ __forceinline__ f32x4_t mfma16(u16x8_t a, u16x8_t b, f32x4_t c) {
  return __builtin_amdgcn_mfma_f32_16x16x32_bf16(
      __builtin_bit_cast(bf16x8_t, a), __builtin_bit_cast(bf16x8_t, b), c, 0, 0, 0);
}

__device__ __forceinline__ float sigmoid_f(float v) { return 1.0f / (1.0f + __expf(-v)); }
__device__ __forceinline__ float tanh_f(float v) { return 1.0f - 2.0f / (__expf(2.0f * v) + 1.0f); }

// Grid 1024 = 128 t x 8 d-tiles. Wave wv stages w-rows wv*4..+4, computes b-rows wv*16..+16.
__global__ __launch_bounds__(256, 2) void lstm_gates_kernel(
    const float* __restrict__ x, const float* __restrict__ w, float* __restrict__ out) {
  __shared__ char lds[2][16384];  // 16 rows x 1024B (8 steps x [hi 64B | lo 64B])
  const int lane = threadIdx.x & 63;
  const int wv = threadIdx.x >> 6;
  const int bid = blockIdx.x;
  // XCD swizzle: 8 d-tiles of one t share an XCD -> x[t] L2-resident.
  const int work = (bid & 7) * 128 + (bid >> 3);
  const int t = work >> 3;
  const int d0 = (work & 7) << 6;

  const int c = lane & 15;   // frag row/col index
  const int kg = lane >> 4;  // k-subgroup 0..3

  // ---- x A-frags, full K, resident (128 VGPR). b-row wv*16+c, k = st*32+kg*8+j.
  const float* xrow = x + (((size_t)(wv * 16 + c) * T_ + t) << 9) + kg * 8;
  u16x8_t xh[16], xl[16];
#pragma unroll
  for (int st = 0; st < 16; ++st) {
    float4 a = *(const float4*)(xrow + st * 32);
    float4 b = *(const float4*)(xrow + st * 32 + 4);
    cvt8(a, b, xh[st], xl[st]);
  }

  // ---- LDS write addrs (per ISSUE: 4 rows x 1KB K-half; lane holds floats
  // [lane*4, lane*4+4) of each row's 256-float half).
  const int kl = lane * 4;
  const unsigned wst = (unsigned)(((kl >> 5) & 7) * 128);
  const unsigned wlow = (unsigned)((((kl >> 3) & 3) * 16) + ((kl & 4) << 1));
  unsigned wa_hi[4];
#pragma unroll
  for (int i = 0; i < 4; ++i) {
    const int rl = wv * 4 + i;
    wa_hi[i] = (unsigned)(rl * 1024) + wst + (wlow ^ SWZ(rl));
  }
  // Read side: col c, local k-step st (0..7), group kg; lo = hi ^ 64.
  const unsigned q_hi = ((unsigned)(kg * 16)) ^ SWZ(c);
  const unsigned rbase = (unsigned)(c * 1024);

  const int grow[3] = {0, 1024, 1536};  // gate row bases i, g(2D), o(3D); f skipped
  const char* wt = (const char*)w + ((size_t)t << 22) + (size_t)d0 * 2048;

  f32x4_t acc[3];
#pragma unroll
  for (int g = 0; g < 3; ++g) acc[g] = (f32x4_t){0.f, 0.f, 0.f, 0.f};

  float4 rs0[4], rs1[4];

  // substage SS = cg*6 + g*2 + kh: rows grow[g]+cg*16+wv*4..+4, K-half kh.
#define WOFF(SS)                                                                \
  ((size_t)(grow[((SS) % 6) >> 1] + ((SS) / 6) * 16 + wv * 4) * 2048 +          \
   (size_t)((SS) & 1) * 1024)

#define ISSUE(SS, RS)                                                           \
  do {                                                                          \
    const char* gb_ = wt + WOFF(SS) + lane * 16;                                \
    _Pragma("unroll") for (int i_ = 0; i_ < 4; ++i_)                            \
        RS[i_] = *(const float4*)(gb_ + (size_t)i_ * 2048);                     \
  } while (0)

#define WRITE(SS, RS)                                                           \
  do {                                                                          \
    char* lb_ = &lds[(SS) & 1][0];                                              \
    _Pragma("unroll") for (int i_ = 0; i_ < 4; ++i_) {                          \
      u16x4_t h_, l_;                                                           \
      cvt4(RS[i_], h_, l_);                                                     \
      *(u16x4_t*)(lb_ + wa_hi[i_]) = h_;                                        \
      *(u16x4_t*)(lb_ + (wa_hi[i_] ^ 64u)) = l_;                                \
    }                                                                           \
  } while (0)

#define BARRIER asm volatile("s_waitcnt lgkmcnt(0)\n\ts_barrier" ::: "memory")

#define COMPUTE(SS)                                                             \
  do {                                                                          \
    const char* lb_ = &lds[(SS) & 1][0];                                        \
    const int g_ = ((SS) % 6) >> 1, kh_ = (SS) & 1;                             \
    _Pragma("unroll") for (int st_ = 0; st_ < 8; ++st_) {                       \
      u16x8_t wh_ = *(const u16x8_t*)(lb_ + rbase + st_ * 128 + q_hi);          \
      u16x8_t wl_ = *(const u16x8_t*)(lb_ + rbase + st_ * 128 + (q_hi ^ 64u));  \
      acc[g_] = mfma16(xh[kh_ * 8 + st_], wh_, acc[g_]);                        \
      acc[g_] = mfma16(xh[kh_ * 8 + st_], wl_, acc[g_]);                        \
      acc[g_] = mfma16(xl[kh_ * 8 + st_], wh_, acc[g_]);                        \
    }                                                                           \
  } while (0)

#define STEP(SS, RS)                        \
  WRITE(SS, RS);                            \
  if ((SS) + 2 < 24) ISSUE((SS) + 2, RS);   \
  BARRIER;                                  \
  COMPUTE(SS)

  // Per-cg epilogue: LSTM activation, store 16 cols, reset acc.
#define EPILOG(CG)                                                              \
  do {                                                                          \
    _Pragma("unroll") for (int j_ = 0; j_ < 4; ++j_) {                          \
      float iv_ = acc[0][j_], gv_ = acc[1][j_], ov_ = acc[2][j_];               \
      float cc_ = sigmoid_f(iv_) * tanh_f(gv_);                                 \
      float h_ = sigmoid_f(ov_) * tanh_f(cc_);                                  \
      int b_ = wv * 16 + kg * 4 + j_;                                           \
      out[(((size_t)b_ * T_ + t) << 9) + d0 + (CG) * 16 + c] = h_;              \
    }                                                                           \
    _Pragma("unroll") for (int g_ = 0; g_ < 3; ++g_)                            \
        acc[g_] = (f32x4_t){0.f, 0.f, 0.f, 0.f};                                \
  } while (0)

  ISSUE(0, rs0);
  ISSUE(1, rs1);

  STEP(0, rs0);  STEP(1, rs1);  STEP(2, rs0);
  STEP(3, rs1);  STEP(4, rs0);  STEP(5, rs1);  EPILOG(0);
  STEP(6, rs0);  STEP(7, rs1);  STEP(8, rs0);
  STEP(9, rs1);  STEP(10, rs0); STEP(11, rs1); EPILOG(1);
  STEP(12, rs0); STEP(13, rs1); STEP(14, rs0);
  STEP(15, rs1); STEP(16, rs0); STEP(17, rs1); EPILOG(2);
  STEP(18, rs0); STEP(19, rs1); STEP(20, rs0);
  STEP(21, rs1); STEP(22, rs0); STEP(23, rs1); EPILOG(3);

#undef EPILOG
#undef STEP
#undef COMPUTE
#undef WRITE
#undef ISSUE
#undef WOFF
}

// One wave per (b,t) row of 512; in-place softmax(20*h).
__global__ __launch_bounds__(256) void softmax_kernel(float* __restrict__ io) {
  const int lane = threadIdx.x & 63;
  const int row = blockIdx.x * 4 + (threadIdx.x >> 6);
  float* p = io + ((size_t)row << 9);
  float4 v0 = *(const float4*)(p + lane * 4);
  float4 v1 = *(const float4*)(p + 256 + lane * 4);
  float l[8] = {20.f * v0.x, 20.f * v0.y, 20.f * v0.z, 20.f * v0.w,
                20.f * v1.x, 20.f * v1.y, 20.f * v1.z, 20.f * v1.w};
  float m = l[0];
#pragma unroll
  for (int j = 1; j < 8; ++j) m = fmaxf(m, l[j]);
#pragma unroll
  for (int o = 32; o > 0; o >>= 1) m = fmaxf(m, __shfl_xor(m, o, 64));
  float e[8], s = 0.f;
#pragma unroll
  for (int j = 0; j < 8; ++j) {
    e[j] = __expf(l[j] - m);
    s += e[j];
  }
#pragma unroll
  for (int o = 32; o > 0; o >>= 1) s += __shfl_xor(s, o, 64);
  float inv = 1.0f / s;
  float4 o0 = {e[0] * inv, e[1] * inv, e[2] * inv, e[3] * inv};
  float4 o1 = {e[4] * inv, e[5] * inv, e[6] * inv, e[7] * inv};
  *(float4*)(p + lane * 4) = o0;
  *(float4*)(p + 256 + lane * 4) = o1;
}

extern "C" void kernel_launch(void* const* d_in, const int* in_sizes, int n_in,
                              void* d_out, int out_size, void* d_ws, size_t ws_size,
                              hipStream_t stream) {
  const float* x = (const float*)d_in[0];
  const float* w = (const float*)d_in[1];
  float* out = (float*)d_out;
  lstm_gates_kernel<<<T_ * 8, 256, 0, stream>>>(x, w, out);
  softmax_kernel<<<(B_ * T_) / 4, 256, 0, stream>>>(out);
}